// Round 1
// baseline (465.440 us; speedup 1.0000x reference)
//
#include <hip/hip_runtime.h>

// DenseGINConv fused: out = mask * ( relu( ((1+eps)*x + adj@x) @ W1 + b1 ) @ W2 + b2 )
// B=64, N=1024, F_IN=64, F_HID=128, F_OUT=64, fp32.
//
// Grid: 1024 blocks (64 batches x 16 row-tiles of 64 rows), 256 threads.
// Phase A: agg tile via LDS-staged adj/x chunks, fp32 FMA (no fp32 MFMA on CDNA4).
// Phase B: h1 = relu(h @ W1 + b1), W1 from global (L1-resident).
// Phase C: out = h1 @ W2 + b2, masked.
// LDS: region1 (33 KB, xs+as in phase A, h1s in B/C) + hs (16 KB) = 49 KB -> 3 blocks/CU.

#define N_    1024
#define FIN   64
#define FHID  128
#define FOUT  64
#define JT    64
#define AS_LD 68     // adj tile leading dim pad: 4-row stride = 272 floats -> banks {0,16}, 2-way = free
#define H1_LD 132    // h1 leading dim pad: 4-row stride = 528 floats -> banks {0,16}, 2-way = free

__global__ __launch_bounds__(256) void gin_fused(
    const float* __restrict__ x, const float* __restrict__ adj,
    const int* __restrict__ mask, const float* __restrict__ W1,
    const float* __restrict__ b1, const float* __restrict__ W2,
    const float* __restrict__ b2, const float* __restrict__ epsp,
    float* __restrict__ out)
{
    __shared__ float region1[8448];   // phase A: xs[4096] + as[64*68]=4352 ; phase B/C: h1s[64*132]=8448
    __shared__ float hs[64 * 64];     // h tile (agg + (1+eps)x), persists A->B

    float* xs  = region1;             // x chunk  [JT][FIN]
    float* as_ = region1 + 4096;      // adj tile [64][AS_LD]
    float* h1s = region1;             // h1 tile  [64][H1_LD] (aliases xs/as after phase A)

    const int t  = threadIdx.x;
    const int b  = blockIdx.x >> 4;
    const int i0 = (blockIdx.x & 15) * 64;

    // Phase A / C thread mapping: 4 rows x 4 features per thread
    const int fi = (t & 15) * 4;      // feature col base
    const int ri = (t >> 4) * 4;      // local row base

    const float* xb   = x   + (size_t)b * N_ * FIN;
    const float* adjb = adj + (size_t)b * N_ * N_ + (size_t)i0 * N_;

    float4 acc[4];
    #pragma unroll
    for (int ii = 0; ii < 4; ++ii) acc[ii] = make_float4(0.f, 0.f, 0.f, 0.f);

    // ---------------- Phase A: agg = adj @ x ----------------
    for (int jc = 0; jc < N_ / JT; ++jc) {
        const int j0 = jc * JT;

        // stage x[b, j0:j0+64, :] -- contiguous 16 KB
        const float4* xsrc = reinterpret_cast<const float4*>(xb + j0 * FIN);
        #pragma unroll
        for (int k = 0; k < 4; ++k) {
            const int l = t + 256 * k;
            reinterpret_cast<float4*>(xs)[l] = xsrc[l];
        }
        // stage adj[b, i0:i0+64, j0:j0+64] -> as_[r][c], padded stride
        #pragma unroll
        for (int k = 0; k < 4; ++k) {
            const int l  = t + 256 * k;
            const int r  = l >> 4;
            const int c4 = (l & 15) * 4;
            const float4 v = *reinterpret_cast<const float4*>(adjb + (size_t)r * N_ + j0 + c4);
            *reinterpret_cast<float4*>(&as_[r * AS_LD + c4]) = v;
        }
        __syncthreads();

        #pragma unroll 4
        for (int jj = 0; jj < JT; ++jj) {
            const float4 xv = *reinterpret_cast<const float4*>(&xs[jj * FIN + fi]);
            const float a0 = as_[(ri + 0) * AS_LD + jj];
            const float a1 = as_[(ri + 1) * AS_LD + jj];
            const float a2 = as_[(ri + 2) * AS_LD + jj];
            const float a3 = as_[(ri + 3) * AS_LD + jj];
            acc[0].x += a0 * xv.x; acc[0].y += a0 * xv.y; acc[0].z += a0 * xv.z; acc[0].w += a0 * xv.w;
            acc[1].x += a1 * xv.x; acc[1].y += a1 * xv.y; acc[1].z += a1 * xv.z; acc[1].w += a1 * xv.w;
            acc[2].x += a2 * xv.x; acc[2].y += a2 * xv.y; acc[2].z += a2 * xv.z; acc[2].w += a2 * xv.w;
            acc[3].x += a3 * xv.x; acc[3].y += a3 * xv.y; acc[3].z += a3 * xv.z; acc[3].w += a3 * xv.w;
        }
        __syncthreads();
    }

    // h = (1+eps)*x + agg  -> hs
    const float se = 1.0f + epsp[0];
    #pragma unroll
    for (int ii = 0; ii < 4; ++ii) {
        const float4 xv = *reinterpret_cast<const float4*>(xb + (size_t)(i0 + ri + ii) * FIN + fi);
        float4 h;
        h.x = acc[ii].x + se * xv.x;
        h.y = acc[ii].y + se * xv.y;
        h.z = acc[ii].z + se * xv.z;
        h.w = acc[ii].w + se * xv.w;
        *reinterpret_cast<float4*>(&hs[(ri + ii) * FIN + fi]) = h;
    }
    __syncthreads();

    // ---------------- Phase B: h1 = relu(h @ W1 + b1) ----------------
    {
        const int k4 = (t & 31) * 4;   // hidden col base (0..124)
        const int rb = (t >> 5) * 8;   // row base (0..56), 8 rows/thread
        float4 hacc[8];
        const float4 b1v = *reinterpret_cast<const float4*>(b1 + k4);
        #pragma unroll
        for (int r = 0; r < 8; ++r) hacc[r] = b1v;

        #pragma unroll 4
        for (int j = 0; j < FIN; ++j) {
            const float4 w1v = *reinterpret_cast<const float4*>(W1 + j * FHID + k4);
            #pragma unroll
            for (int r = 0; r < 8; ++r) {
                const float hv = hs[(rb + r) * FIN + j];
                hacc[r].x += hv * w1v.x; hacc[r].y += hv * w1v.y;
                hacc[r].z += hv * w1v.z; hacc[r].w += hv * w1v.w;
            }
        }
        #pragma unroll
        for (int r = 0; r < 8; ++r) {
            float4 v;
            v.x = fmaxf(hacc[r].x, 0.f); v.y = fmaxf(hacc[r].y, 0.f);
            v.z = fmaxf(hacc[r].z, 0.f); v.w = fmaxf(hacc[r].w, 0.f);
            *reinterpret_cast<float4*>(&h1s[(rb + r) * H1_LD + k4]) = v;
        }
    }
    __syncthreads();

    // ---------------- Phase C: out = mask * (h1 @ W2 + b2) ----------------
    {
        float4 oacc[4];
        const float4 b2v = *reinterpret_cast<const float4*>(b2 + fi);
        #pragma unroll
        for (int ii = 0; ii < 4; ++ii) oacc[ii] = b2v;

        #pragma unroll 4
        for (int j = 0; j < FHID; ++j) {
            const float4 w2v = *reinterpret_cast<const float4*>(W2 + j * FOUT + fi);
            #pragma unroll
            for (int ii = 0; ii < 4; ++ii) {
                const float hv = h1s[(ri + ii) * H1_LD + j];
                oacc[ii].x += hv * w2v.x; oacc[ii].y += hv * w2v.y;
                oacc[ii].z += hv * w2v.z; oacc[ii].w += hv * w2v.w;
            }
        }
        #pragma unroll
        for (int ii = 0; ii < 4; ++ii) {
            const int gi = i0 + ri + ii;
            const int m  = mask[b * N_ + gi];
            float4 o = oacc[ii];
            if (!m) o = make_float4(0.f, 0.f, 0.f, 0.f);
            *reinterpret_cast<float4*>(out + ((size_t)b * N_ + gi) * FOUT + fi) = o;
        }
    }
}

extern "C" void kernel_launch(void* const* d_in, const int* in_sizes, int n_in,
                              void* d_out, int out_size, void* d_ws, size_t ws_size,
                              hipStream_t stream) {
    const float* x    = (const float*)d_in[0];
    const float* adj  = (const float*)d_in[1];
    const int*   mask = (const int*)  d_in[2];
    const float* W1   = (const float*)d_in[3];
    const float* b1   = (const float*)d_in[4];
    const float* W2   = (const float*)d_in[5];
    const float* b2   = (const float*)d_in[6];
    const float* eps  = (const float*)d_in[7];
    float* out = (float*)d_out;

    dim3 grid(64 * 16);   // 64 batches x 16 row-tiles
    dim3 block(256);
    gin_fused<<<grid, block, 0, stream>>>(x, adj, mask, W1, b1, W2, b2, eps, out);
}

// Round 4
// 428.368 us; speedup vs baseline: 1.0865x; 1.0865x over previous
//
#include <hip/hip_runtime.h>

// DenseGINConv fused: out = mask * ( relu( ((1+eps)*x + adj@x) @ W1 + b1 ) @ W2 + b2 )
// B=64, N=1024, F_IN=64, F_HID=128, F_OUT=64, fp32 in/out.
//
// Round 4: einsum via mfma_f32_32x32x16_bf16 (m74/m101 end-to-end-verified
// layout combo: A m=lane&31,k=8*(lane>>5)+e; B mirror; C/D col=lane&31,
// row=(reg&3)+8*(reg>>2)+4*(lane>>5)). Staging identical to round 3.
// Each of 4 waves owns one 32x32 quadrant of the 64x64 output tile.
//
// Grid: 1024 blocks (64 batches x 16 row-tiles of 64), 256 threads = 4 waves.
// LDS: region1 (asf+xtf bf16 frags 18.4 KB / h1s 33.8 KB, aliased) + hs 17.4 KB.

#define N_    1024
#define FIN   64
#define FHID  128
#define FOUT  64
#define HS_LD 68
#define H1_LD 132
#define FROW  9      // s16x8 frag groups per tile row (8 used + 1 pad -> 144 B stride)

typedef __attribute__((ext_vector_type(16))) float f32x16;
typedef __attribute__((ext_vector_type(8)))  short s16x8;

__device__ inline short f2bf(float f) {
    union { float f; unsigned int u; } v; v.f = f;
    unsigned int r = v.u + 0x7fffu + ((v.u >> 16) & 1u);   // RNE
    return (short)(r >> 16);
}

__global__ __launch_bounds__(256) void gin_fused(
    const float* __restrict__ x, const float* __restrict__ adj,
    const int* __restrict__ mask, const float* __restrict__ W1,
    const float* __restrict__ b1, const float* __restrict__ W2,
    const float* __restrict__ b2, const float* __restrict__ epsp,
    float* __restrict__ out)
{
    // region1: phase A = asf[64][9] + xtf[64][9] s16x8 frags (18432 B);
    //          phase B/C = h1s float[64*132] (33792 B). 2112 frags total.
    __shared__ s16x8 region1[2112];
    __shared__ float hs[64 * HS_LD];

    s16x8 (*asf)[FROW] = reinterpret_cast<s16x8 (*)[FROW]>(region1);        // adj tile (rows = i)
    s16x8 (*xtf)[FROW] = reinterpret_cast<s16x8 (*)[FROW]>(region1 + 576);  // xT tile  (rows = f)
    float* h1s = reinterpret_cast<float*>(region1);

    const int t    = threadIdx.x;
    const int lane = t & 63;
    const int w    = t >> 6;
    const int b    = blockIdx.x >> 4;
    const int i0   = (blockIdx.x & 15) * 64;

    const float* xb   = x   + (size_t)b * N_ * FIN;
    const float* adjb = adj + (size_t)b * N_ * N_ + (size_t)i0 * N_;

    // 32x32x16 MFMA addressing
    const int l31  = lane & 31;
    const int half = lane >> 5;
    const int mrow = (w & 1) * 32;       // quadrant row base
    const int ncol = (w >> 1) * 32;      // quadrant col base

    // staging mapping (identical to round 3)
    const int sr = t >> 2;               // adj tile row 0..63
    const int sc = (t & 3) * 16;         // col base
    const int sg = (t & 3) * 2;          // frag group base

    f32x16 acc;
    #pragma unroll
    for (int r = 0; r < 16; ++r) acc[r] = 0.f;

    // ---------------- Phase A: agg = adj @ x  (bf16 MFMA 32x32x16) ----------------
    for (int jc = 0; jc < N_ / 64; ++jc) {
        const int j0 = jc * 64;

        // stage adj[b, i0:i0+64, j0:j0+64] -> bf16 frags
        {
            const float* ar = adjb + (size_t)sr * N_ + j0 + sc;
            const float4 p0 = *reinterpret_cast<const float4*>(ar);
            const float4 p1 = *reinterpret_cast<const float4*>(ar + 4);
            const float4 p2 = *reinterpret_cast<const float4*>(ar + 8);
            const float4 p3 = *reinterpret_cast<const float4*>(ar + 12);
            s16x8 f0, f1;
            f0[0] = f2bf(p0.x); f0[1] = f2bf(p0.y); f0[2] = f2bf(p0.z); f0[3] = f2bf(p0.w);
            f0[4] = f2bf(p1.x); f0[5] = f2bf(p1.y); f0[6] = f2bf(p1.z); f0[7] = f2bf(p1.w);
            f1[0] = f2bf(p2.x); f1[1] = f2bf(p2.y); f1[2] = f2bf(p2.z); f1[3] = f2bf(p2.w);
            f1[4] = f2bf(p3.x); f1[5] = f2bf(p3.y); f1[6] = f2bf(p3.z); f1[7] = f2bf(p3.w);
            asf[sr][sg]     = f0;
            asf[sr][sg + 1] = f1;
        }
        // stage x[b, j0:j0+64, :]^T -> xtf[f][j-frag]; lane=f, wave w covers j-window 16w..16w+15
        {
            s16x8 q0, q1;
            #pragma unroll
            for (int jj = 0; jj < 8; ++jj)
                q0[jj] = f2bf(xb[(size_t)(j0 + w * 16 + jj) * FIN + lane]);
            #pragma unroll
            for (int jj = 0; jj < 8; ++jj)
                q1[jj] = f2bf(xb[(size_t)(j0 + w * 16 + 8 + jj) * FIN + lane]);
            xtf[lane][2 * w]     = q0;
            xtf[lane][2 * w + 1] = q1;
        }
        __syncthreads();

        // 4 k-steps of 16; frag group = 2s + half
        #pragma unroll
        for (int s = 0; s < 4; ++s) {
            const s16x8 a  = asf[mrow + l31][2 * s + half];
            const s16x8 bf = xtf[ncol + l31][2 * s + half];
            acc = __builtin_amdgcn_mfma_f32_32x32x16_bf16(a, bf, acc, 0, 0, 0);
        }
        __syncthreads();
    }

    // h = (1+eps)*x + agg -> hs
    // C/D layout (m74/m101): col = lane&31, row = (reg&3) + 8*(reg>>2) + 4*(lane>>5)
    {
        const float se = 1.0f + epsp[0];
        const int col = ncol + l31;
        #pragma unroll
        for (int reg = 0; reg < 16; ++reg) {
            const int row = mrow + (reg & 3) + 8 * (reg >> 2) + 4 * half;
            const float xv = xb[(size_t)(i0 + row) * FIN + col];
            hs[row * HS_LD + col] = acc[reg] + se * xv;
        }
    }
    __syncthreads();

    // ---------------- Phase B: h1 = relu(h @ W1 + b1) ----------------
    {
        const int k4 = (t & 31) * 4;
        const int rb = (t >> 5) * 8;
        float4 hacc[8];
        const float4 b1v = *reinterpret_cast<const float4*>(b1 + k4);
        #pragma unroll
        for (int r = 0; r < 8; ++r) hacc[r] = b1v;

        #pragma unroll 4
        for (int j = 0; j < FIN; ++j) {
            const float4 w1v = *reinterpret_cast<const float4*>(W1 + j * FHID + k4);
            #pragma unroll
            for (int r = 0; r < 8; ++r) {
                const float hv = hs[(rb + r) * HS_LD + j];
                hacc[r].x += hv * w1v.x; hacc[r].y += hv * w1v.y;
                hacc[r].z += hv * w1v.z; hacc[r].w += hv * w1v.w;
            }
        }
        #pragma unroll
        for (int r = 0; r < 8; ++r) {
            float4 v;
            v.x = fmaxf(hacc[r].x, 0.f); v.y = fmaxf(hacc[r].y, 0.f);
            v.z = fmaxf(hacc[r].z, 0.f); v.w = fmaxf(hacc[r].w, 0.f);
            *reinterpret_cast<float4*>(&h1s[(rb + r) * H1_LD + k4]) = v;
        }
    }
    __syncthreads();

    // ---------------- Phase C: out = mask * (h1 @ W2 + b2) ----------------
    {
        const int fi = (t & 15) * 4;
        const int ri = (t >> 4) * 4;
        float4 oacc[4];
        const float4 b2v = *reinterpret_cast<const float4*>(b2 + fi);
        #pragma unroll
        for (int ii = 0; ii < 4; ++ii) oacc[ii] = b2v;

        #pragma unroll 4
        for (int j = 0; j < FHID; ++j) {
            const float4 w2v = *reinterpret_cast<const float4*>(W2 + j * FOUT + fi);
            #pragma unroll
            for (int ii = 0; ii < 4; ++ii) {
                const float hv = h1s[(ri + ii) * H1_LD + j];
                oacc[ii].x += hv * w2v.x; oacc[ii].y += hv * w2v.y;
                oacc[ii].z += hv * w2v.z; oacc[ii].w += hv * w2v.w;
            }
        }
        #pragma unroll
        for (int ii = 0; ii < 4; ++ii) {
            const int gi = i0 + ri + ii;
            const int m  = mask[b * N_ + gi];
            float4 o = oacc[ii];
            if (!m) o = make_float4(0.f, 0.f, 0.f, 0.f);
            *reinterpret_cast<float4*>(out + ((size_t)b * N_ + gi) * FOUT + fi) = o;
        }
    }
}

extern "C" void kernel_launch(void* const* d_in, const int* in_sizes, int n_in,
                              void* d_out, int out_size, void* d_ws, size_t ws_size,
                              hipStream_t stream) {
    const float* x    = (const float*)d_in[0];
    const float* adj  = (const float*)d_in[1];
    const int*   mask = (const int*)  d_in[2];
    const float* W1   = (const float*)d_in[3];
    const float* b1   = (const float*)d_in[4];
    const float* W2   = (const float*)d_in[5];
    const float* b2   = (const float*)d_in[6];
    const float* eps  = (const float*)d_in[7];
    float* out = (float*)d_out;

    dim3 grid(64 * 16);
    dim3 block(256);
    gin_fused<<<grid, block, 0, stream>>>(x, adj, mask, W1, b1, W2, b2, eps, out);
}

// Round 5
// 415.974 us; speedup vs baseline: 1.1189x; 1.0298x over previous
//
#include <hip/hip_runtime.h>

// DenseGINConv fused: out = mask * ( relu( ((1+eps)*x + adj@x) @ W1 + b1 ) @ W2 + b2 )
// B=64, N=1024, F_IN=64, F_HID=128, F_OUT=64, fp32 in/out.
//
// Round 5: latency-oriented rework of phase A.
//  - xt_pack pre-kernel: x -> bf16 B-fragment-major in d_ws (8 MB); main kernel
//    loads B-frags directly from global (L2-hot), no x LDS staging.
//  - adj: 128-wide j-chunks (8 chunks), double-buffered LDS, register prefetch
//    issued right after each barrier; ONE barrier per chunk.
//  - einsum: mfma_f32_32x32x16_bf16 (m74/m101-verified layouts), fp32 accum.
// Phases B/C (MLP) unchanged from round 4 (proven).
//
// LDS: asf dbuf 2x64x17 frags = 34816 B (h1s 33792 aliases it) + hs 17408 B
//      = 52224 B -> 3 blocks/CU. __launch_bounds__(256,3).

#define N_     1024
#define FIN    64
#define FHID   128
#define FOUT   64
#define HS_LD  68
#define H1_LD  132
#define FROW   17      // frags per adj row: 16 used + 1 pad -> 272 B stride (conflict-free reads)
#define NCHUNK 8       // j-chunks of 128
#define KSPC   8       // k-steps (of 16) per chunk

typedef __attribute__((ext_vector_type(16))) float f32x16;
typedef __attribute__((ext_vector_type(8)))  short s16x8;

__device__ inline short f2bf(float f) {
    union { float f; unsigned int u; } v; v.f = f;
    unsigned int r = v.u + 0x7fffu + ((v.u >> 16) & 1u);   // RNE
    return (short)(r >> 16);
}

// ---------------- pre-kernel: pack x -> bf16 B-fragment-major ----------------
// Row g = ((b*64 + ks)*2 + ng)*32 + n holds k=0..15 of B[n | ng] for k-step ks:
//   xt_row[g][k] = bf16( x[b][ks*16 + k][ng*32 + n] )
// 16 bf16 = 32 B per row, stored as 2 s16x8 units at [2g], [2g+1].
__global__ __launch_bounds__(256) void xt_pack(const float* __restrict__ x,
                                               s16x8* __restrict__ xt)
{
    const int g  = blockIdx.x * 256 + threadIdx.x;   // 0 .. 262143
    const int n  = g & 31;
    const int ng = (g >> 5) & 1;
    const int ks = (g >> 6) & 63;
    const int b  = g >> 12;
    const int f  = ng * 32 + n;

    s16x8 u0, u1;
    #pragma unroll
    for (int k = 0; k < 8; ++k)
        u0[k] = f2bf(x[(size_t)(b * N_ + ks * 16 + k) * FIN + f]);
    #pragma unroll
    for (int k = 0; k < 8; ++k)
        u1[k] = f2bf(x[(size_t)(b * N_ + ks * 16 + 8 + k) * FIN + f]);
    xt[2 * g]     = u0;
    xt[2 * g + 1] = u1;
}

// ---------------- main kernel ----------------
__global__ __launch_bounds__(256, 3) void gin_main(
    const float* __restrict__ x, const float* __restrict__ adj,
    const int* __restrict__ mask, const float* __restrict__ W1,
    const float* __restrict__ b1, const float* __restrict__ W2,
    const float* __restrict__ b2, const float* __restrict__ epsp,
    const s16x8* __restrict__ xt, float* __restrict__ out)
{
    __shared__ s16x8 region[2 * 64 * FROW];   // adj bf16 dbuf (34816 B); h1s aliases
    __shared__ float hs[64 * HS_LD];

    s16x8 (*asf)[64][FROW] = reinterpret_cast<s16x8 (*)[64][FROW]>(region);
    float* h1s = reinterpret_cast<float*>(region);

    const int t    = threadIdx.x;
    const int lane = t & 63;
    const int w    = t >> 6;
    const int b    = blockIdx.x >> 4;
    const int i0   = (blockIdx.x & 15) * 64;

    const float* xb   = x   + (size_t)b * N_ * FIN;
    const float* adjb = adj + (size_t)b * N_ * N_ + (size_t)i0 * N_;

    // 32x32x16 MFMA addressing (m74/m101-verified)
    const int l31  = lane & 31;
    const int half = lane >> 5;
    const int mrow = (w & 1) * 32;
    const int ncol = (w >> 1) * 32;
    const int ngq  = (w >> 1);

    // adj staging: 4 threads/row, 32 floats (4 frags) each
    const int sr  = t >> 2;
    const int scf = (t & 3) * 32;
    const int sfg = (t & 3) * 4;
    const float* arow_p = adjb + (size_t)sr * N_ + scf;

    // B-frag per-lane offset within a (b,ks,ng) 1 KB group (64 units)
    const int bfl = l31 * 2 + half;
    const size_t bgbase = (size_t)(b * 64) * 2 + ngq;   // group index = (b*64+ks)*2+ng

    f32x16 acc;
    #pragma unroll
    for (int r = 0; r < 16; ++r) acc[r] = 0.f;

    float4 pa[8];        // raw adj prefetch (next chunk)
    s16x8  pbc[KSPC];    // B-frags, current chunk
    s16x8  pbn[KSPC];    // B-frags, next chunk

    // ---- prologue: chunk 0 ----
    #pragma unroll
    for (int q = 0; q < 8; ++q)
        pa[q] = *reinterpret_cast<const float4*>(arow_p + 0 * 128 + q * 4);
    #pragma unroll
    for (int s = 0; s < KSPC; ++s)
        pbc[s] = xt[(bgbase + (size_t)(0 * KSPC + s) * 2) * 64 + bfl];
    #pragma unroll
    for (int q = 0; q < 4; ++q) {
        const float4 u = pa[2 * q], v = pa[2 * q + 1];
        s16x8 fr;
        fr[0] = f2bf(u.x); fr[1] = f2bf(u.y); fr[2] = f2bf(u.z); fr[3] = f2bf(u.w);
        fr[4] = f2bf(v.x); fr[5] = f2bf(v.y); fr[6] = f2bf(v.z); fr[7] = f2bf(v.w);
        asf[0][sr][sfg + q] = fr;
    }
    __syncthreads();

    // ---- pipelined chunk loop: issue(c+1) early, compute(c), stage(c+1), barrier ----
    #pragma unroll
    for (int c = 0; c < NCHUNK; ++c) {
        if (c + 1 < NCHUNK) {
            #pragma unroll
            for (int q = 0; q < 8; ++q)
                pa[q] = *reinterpret_cast<const float4*>(arow_p + (c + 1) * 128 + q * 4);
            #pragma unroll
            for (int s = 0; s < KSPC; ++s)
                pbn[s] = xt[(bgbase + (size_t)((c + 1) * KSPC + s) * 2) * 64 + bfl];
        }
        // compute chunk c
        #pragma unroll
        for (int s = 0; s < KSPC; ++s) {
            const s16x8 a = asf[c & 1][mrow + l31][2 * s + half];
            acc = __builtin_amdgcn_mfma_f32_32x32x16_bf16(a, pbc[s], acc, 0, 0, 0);
        }
        if (c + 1 < NCHUNK) {
            // stage chunk c+1 into the other buffer
            #pragma unroll
            for (int q = 0; q < 4; ++q) {
                const float4 u = pa[2 * q], v = pa[2 * q + 1];
                s16x8 fr;
                fr[0] = f2bf(u.x); fr[1] = f2bf(u.y); fr[2] = f2bf(u.z); fr[3] = f2bf(u.w);
                fr[4] = f2bf(v.x); fr[5] = f2bf(v.y); fr[6] = f2bf(v.z); fr[7] = f2bf(v.w);
                asf[(c + 1) & 1][sr][sfg + q] = fr;
            }
            #pragma unroll
            for (int s = 0; s < KSPC; ++s) pbc[s] = pbn[s];
            __syncthreads();
        }
    }

    // h = (1+eps)*x + agg -> hs  (C/D: col=lane&31, row=(reg&3)+8*(reg>>2)+4*half)
    {
        const float se = 1.0f + epsp[0];
        const int col = ncol + l31;
        #pragma unroll
        for (int reg = 0; reg < 16; ++reg) {
            const int row = mrow + (reg & 3) + 8 * (reg >> 2) + 4 * half;
            const float xv = xb[(size_t)(i0 + row) * FIN + col];
            hs[row * HS_LD + col] = acc[reg] + se * xv;
        }
    }
    __syncthreads();

    // ---------------- Phase B: h1 = relu(h @ W1 + b1) ----------------
    {
        const int k4 = (t & 31) * 4;
        const int rb = (t >> 5) * 8;
        float4 hacc[8];
        const float4 b1v = *reinterpret_cast<const float4*>(b1 + k4);
        #pragma unroll
        for (int r = 0; r < 8; ++r) hacc[r] = b1v;

        #pragma unroll 4
        for (int j = 0; j < FIN; ++j) {
            const float4 w1v = *reinterpret_cast<const float4*>(W1 + j * FHID + k4);
            #pragma unroll
            for (int r = 0; r < 8; ++r) {
                const float hv = hs[(rb + r) * HS_LD + j];
                hacc[r].x += hv * w1v.x; hacc[r].y += hv * w1v.y;
                hacc[r].z += hv * w1v.z; hacc[r].w += hv * w1v.w;
            }
        }
        #pragma unroll
        for (int r = 0; r < 8; ++r) {
            float4 v;
            v.x = fmaxf(hacc[r].x, 0.f); v.y = fmaxf(hacc[r].y, 0.f);
            v.z = fmaxf(hacc[r].z, 0.f); v.w = fmaxf(hacc[r].w, 0.f);
            *reinterpret_cast<float4*>(&h1s[(rb + r) * H1_LD + k4]) = v;
        }
    }
    __syncthreads();

    // ---------------- Phase C: out = mask * (h1 @ W2 + b2) ----------------
    {
        const int fi = (t & 15) * 4;
        const int ri = (t >> 4) * 4;
        float4 oacc[4];
        const float4 b2v = *reinterpret_cast<const float4*>(b2 + fi);
        #pragma unroll
        for (int ii = 0; ii < 4; ++ii) oacc[ii] = b2v;

        #pragma unroll 4
        for (int j = 0; j < FHID; ++j) {
            const float4 w2v = *reinterpret_cast<const float4*>(W2 + j * FOUT + fi);
            #pragma unroll
            for (int ii = 0; ii < 4; ++ii) {
                const float hv = h1s[(ri + ii) * H1_LD + j];
                oacc[ii].x += hv * w2v.x; oacc[ii].y += hv * w2v.y;
                oacc[ii].z += hv * w2v.z; oacc[ii].w += hv * w2v.w;
            }
        }
        #pragma unroll
        for (int ii = 0; ii < 4; ++ii) {
            const int gi = i0 + ri + ii;
            const int m  = mask[b * N_ + gi];
            float4 o = oacc[ii];
            if (!m) o = make_float4(0.f, 0.f, 0.f, 0.f);
            *reinterpret_cast<float4*>(out + ((size_t)b * N_ + gi) * FOUT + fi) = o;
        }
    }
}

extern "C" void kernel_launch(void* const* d_in, const int* in_sizes, int n_in,
                              void* d_out, int out_size, void* d_ws, size_t ws_size,
                              hipStream_t stream) {
    const float* x    = (const float*)d_in[0];
    const float* adj  = (const float*)d_in[1];
    const int*   mask = (const int*)  d_in[2];
    const float* W1   = (const float*)d_in[3];
    const float* b1   = (const float*)d_in[4];
    const float* W2   = (const float*)d_in[5];
    const float* b2   = (const float*)d_in[6];
    const float* eps  = (const float*)d_in[7];
    float* out = (float*)d_out;
    s16x8* xt = (s16x8*)d_ws;   // 8 MB: 524288 units

    xt_pack<<<dim3(1024), dim3(256), 0, stream>>>(x, xt);
    gin_main<<<dim3(64 * 16), dim3(256), 0, stream>>>(x, adj, mask, W1, b1, W2, b2, eps, xt, out);
}